// Round 15
// baseline (191.407 us; speedup 1.0000x reference)
//
#include <hip/hip_runtime.h>
#include <hip/hip_bf16.h>

typedef __attribute__((ext_vector_type(8))) short bf16x8;
typedef __attribute__((ext_vector_type(4))) float f32x4;
typedef __attribute__((ext_vector_type(4))) unsigned int u32x4;
typedef __attribute__((ext_vector_type(2))) unsigned int u32x2;

#define NB 2048

static __device__ __forceinline__ unsigned short f2bf(float f) {
  unsigned int u = __builtin_bit_cast(unsigned int, f);
  u += 0x7fffu + ((u >> 16) & 1u);   // RNE
  return (unsigned short)(u >> 16);
}
// HW packed f32->bf16 (RNE), two values into one dword
static __device__ __forceinline__ unsigned int cvtpk(float lo, float hi) {
  unsigned int r;
  asm("v_cvt_pk_bf16_f32 %0, %1, %2" : "=v"(r) : "v"(lo), "v"(hi));
  return r;
}

// ---------------- weight prep (single pass) + fc1-counter zeroing ----------------
// fc1wbF fragment layout: idx = q*4096 + n*32 + kw   (q=k>>5, kw=k&31)
__global__ __launch_bounds__(256) void k_prep(
    const float* __restrict__ w2, const float* __restrict__ fc1w,
    const float* __restrict__ w1, const float* __restrict__ p1,
    const float* __restrict__ p2,
    unsigned short* __restrict__ w2b, unsigned short* __restrict__ fc1wb,
    unsigned short* __restrict__ k1b, int* __restrict__ cnt) {
  const int gid = blockIdx.x * blockDim.x + threadIdx.x;
  if (gid < 401408) {
    const int j0 = gid * 4;               // 4 consecutive kw, same (q, n)
    const int kw = j0 & 31;
    const int n  = (j0 >> 5) & 127;
    const int q  = j0 >> 12;
    f32x4 v = *(const f32x4*)&fc1w[n*12544 + q*32 + kw];
    u32x2 r = { cvtpk(v[0], v[1]), cvtpk(v[2], v[3]) };
    *(u32x2*)&fc1wb[j0] = r;
  } else if (gid < 401408 + 18432) {
    int i = gid - 401408;
    int cin = i & 31;
    int cout = (i >> 5) & 63;
    int kk = i >> 11;          // 0..8
    int ky = kk / 3, kx = kk % 3;
    w2b[i] = f2bf(w2[((cout*32 + cin)*3 + ky)*3 + kx]);
  } else if (gid < 401408 + 18432 + 1024) {
    int t = gid - (401408 + 18432);  // 0..1023
    int o = t >> 5, tap = t & 31;
    unsigned short r = 0;
    if (tap < 25) {
      int a = tap / 5, bcol = tap % 5;
      float acc = 0.f;
      for (int k = 0; k < 26; ++k) {
        float q1 = p1[o*26 + k] + 2.0f;
        float q2 = p2[o*26 + k] + 2.0f;
        float f1 = floorf(q1), f2 = floorf(q2);
        int idx1 = (int)f1 + ((q1 - f1) >= 0.5f ? 1 : 0);
        int idx2 = (int)f2 + ((q2 - f2) >= 0.5f ? 1 : 0);
        if (idx1 == a && idx2 == bcol) acc += w1[o*26 + k];
      }
      r = f2bf(acc);
    }
    k1b[t] = r;
  } else if (gid < 401408 + 18432 + 1024 + 32) {
    cnt[gid - (401408 + 18432 + 1024)] = 0;   // re-zeroed every launch (graph-replay safe)
  }
}

// ---------------- fused conv1(MFMA)+relu -> conv2(MFMA)+relu+maxpool ----------------
// r10 config (best measured: 68us). one block = one image; 3 blocks/CU.
// WARNING (rounds 5 & 11): launch_bounds requesting 4 waves/EU clamps VGPR to
// 64 -> bfr spills to scratch -> FETCH/WRITE balloon. Keep (256,3).
// k_conv is issue-bound (~44% MFMA + ~40% VALU, near-serialized); occupancy
// 25->35% (r12), LDS-read halving (r8) both neutral. Structural at ~68us.
// h1s layout: pixel-major, 4x 16B cin-blocks per pixel, XOR-swizzled.
// h3F OUTPUT fragment layout: idx = mtile*200704 + ks*512 + mi*32 + kw
__global__ __launch_bounds__(256, 3) void k_conv(
    const float* __restrict__ x, const unsigned short* __restrict__ k1b,
    const float* __restrict__ b1, const unsigned short* __restrict__ w2b,
    const float* __restrict__ b2, unsigned short* __restrict__ h3) {
  __shared__ __align__(16) float xs[32*36];              // padded input, stride 36
  __shared__ __align__(16) unsigned short h1s[16*32*32]; // one y-half, swizzled

  const int t = threadIdx.x;
  const int bimg = (blockIdx.x & 7) * 256 + (blockIdx.x >> 3);  // XCD-contiguous
  const int lane = t & 63;
  const int wid = t >> 6;
  const int l15 = lane & 15;
  const int lk = lane >> 4;

  // ---- stage x into xs (zero border) ----
  for (int i = t; i < 1152; i += 256) {
    int iy = i / 36, ix = i - iy*36;
    float v = 0.f;
    if (iy >= 2 && iy < 30 && ix >= 2 && ix < 30)
      v = x[bimg*784 + (iy-2)*28 + (ix-2)];
    xs[i] = v;
  }

  // ---- conv1 operands (registers) ----
  int off[8];                       // per-lane im2col tap offsets (taps>=25 clamp: A rows are 0 there)
  #pragma unroll
  for (int j = 0; j < 8; ++j) {
    int tp = lk*8 + j; tp = tp > 24 ? 24 : tp;
    int ky = tp / 5;
    off[j] = ky*36 + (tp - ky*5);
  }
  const bf16x8 k1a0 = *(const bf16x8*)&k1b[l15*32 + lk*8];
  const bf16x8 k1a1 = *(const bf16x8*)&k1b[(16 + l15)*32 + lk*8];
  f32x4 b1i0, b1i1;                 // MFMA acc-init with bias (row = cout = lk*4+reg)
  #pragma unroll
  for (int r = 0; r < 4; ++r) {
    b1i0[r] = b1[lk*4 + r];
    b1i1[r] = b1[16 + lk*4 + r];
  }

  // ---- conv2 operands (registers) ----
  const int ntp = wid & 1;      // couts ntp*32 .. ntp*32+31
  const int tx  = wid >> 1;     // x half-tile (wave-uniform)
  bf16x8 bfr[2][9];
  #pragma unroll
  for (int nn = 0; nn < 2; ++nn)
    #pragma unroll
    for (int kk = 0; kk < 9; ++kk)
      bfr[nn][kk] = *(const bf16x8*)&w2b[(kk*64 + (ntp*2+nn)*16 + l15)*32 + lk*8];
  f32x4 b2i[2];                 // acc-init (col = cout = l15, same across rows)
  #pragma unroll
  for (int nn = 0; nn < 2; ++nn) {
    float bb = b2[ntp*32 + nn*16 + l15];
    b2i[nn] = (f32x4){bb, bb, bb, bb};
  }
  int colOff[3];                // byte offsets into an h1s row (swizzle is row-independent)
  #pragma unroll
  for (int kx = 0; kx < 3; ++kx) {
    int xk = tx*16 + l15 + kx; xk = xk > 31 ? 31 : xk;   // clamped dummies read zero pads
    colOff[kx] = xk*64 + ((lk ^ ((xk >> 1) & 3)) << 4);
  }

  const int mtile = bimg >> 4, mi = bimg & 15;
  unsigned short* h3m = h3 + (size_t)mtile*200704 + mi*32;

  __syncthreads();

  for (int half = 0; half < 2; ++half) {
    if (half) __syncthreads();          // prev half's conv2 reads done

    // ---- zero pads for this half ----
    {
      u32x4* H = (u32x4*)h1s;
      u32x4 z = {0u,0u,0u,0u};
      const int zrow = half ? 15 : 0;   // full zero row (y'=0 / y'=29)
      if (t < 128) H[zrow*128 + t] = z;
      const int r0 = half ? 0 : 1;      // col pads on the 15 computed rows
      if (t < 240) {                    // 15 rows x 4 px x 4 chunks
        int rr = t >> 4, rem = t & 15;
        int pi = rem >> 2, sub = rem & 3;
        int px = pi == 0 ? 0 : 28 + pi; // x' in {0,29,30,31}
        H[((r0 + rr)*32 + px)*4 + sub] = z;
      }
    }

    // ---- conv1 via MFMA: A=k1[cout][tap], B=im2col[tap][pixel] ----
    const int ybase = half ? 13 : 0;
    for (int tid = wid; tid < 30; tid += 4) {
      const int ty = tid >> 1;                 // 0..14
      const int x0 = (tid & 1) << 4;
      const int yo = ybase + ty;               // conv output row
      const float* bp = &xs[yo*36 + x0 + l15];
      u32x4 bw;
      bw[0] = cvtpk(bp[off[0]], bp[off[1]]);
      bw[1] = cvtpk(bp[off[2]], bp[off[3]]);
      bw[2] = cvtpk(bp[off[4]], bp[off[5]]);
      bw[3] = cvtpk(bp[off[6]], bp[off[7]]);
      const bf16x8 bfrag = __builtin_bit_cast(bf16x8, bw);
      f32x4 d0 = b1i0, d1 = b1i1;
      d0 = __builtin_amdgcn_mfma_f32_16x16x32_bf16(k1a0, bfrag, d0, 0, 0, 0);
      d1 = __builtin_amdgcn_mfma_f32_16x16x32_bf16(k1a1, bfrag, d1, 0, 0, 0);
      // D: col=l15=pixel, row=lk*4+reg=cout -> 4 consecutive couts per lane
      const int xo = x0 + l15;
      if (xo < 28) {
        const int ry = half ? (yo - 13) : (yo + 1);
        const int pix = ry*32 + xo + 1;
        const int swz = (pix >> 1) & 3;
        const int blkbase = (lk >> 1);
        unsigned int w0lo = cvtpk(fmaxf(d0[0], 0.f), fmaxf(d0[1], 0.f));
        unsigned int w0hi = cvtpk(fmaxf(d0[2], 0.f), fmaxf(d0[3], 0.f));
        unsigned int w1lo = cvtpk(fmaxf(d1[0], 0.f), fmaxf(d1[1], 0.f));
        unsigned int w1hi = cvtpk(fmaxf(d1[2], 0.f), fmaxf(d1[3], 0.f));
        char* base = (char*)h1s + pix*64 + (lk & 1)*8;
        *(u32x2*)(base + ((blkbase ^ swz) << 4))       = (u32x2){w0lo, w0hi};
        *(u32x2*)(base + (((2 + blkbase) ^ swz) << 4)) = (u32x2){w1lo, w1hi};
      }
    }
    __syncthreads();

    // ---- conv2 via MFMA ----
    const char* h1c = (const char*)h1s;
    for (int pyl = 0; pyl < 7; ++pyl) {
      const int py = half*7 + pyl;
      const int rbase = pyl*2*2048;
      f32x4 acc[2][2];
      #pragma unroll
      for (int yi = 0; yi < 2; ++yi)
        #pragma unroll
        for (int nn = 0; nn < 2; ++nn) acc[yi][nn] = b2i[nn];
      #pragma unroll
      for (int kx = 0; kx < 3; ++kx) {
        bf16x8 af[4];
        #pragma unroll
        for (int r = 0; r < 4; ++r)
          af[r] = *(const bf16x8*)(h1c + rbase + r*2048 + colOff[kx]);
        #pragma unroll
        for (int ky = 0; ky < 3; ++ky)
          #pragma unroll
          for (int yi = 0; yi < 2; ++yi) {
            acc[yi][0] = __builtin_amdgcn_mfma_f32_16x16x32_bf16(af[yi+ky], bfr[0][ky*3+kx], acc[yi][0], 0, 0, 0);
            acc[yi][1] = __builtin_amdgcn_mfma_f32_16x16x32_bf16(af[yi+ky], bfr[1][ky*3+kx], acc[yi][1], 0, 0, 0);
          }
      }
      // pool-then-relu (monotonic), only on storing lanes
      if (!(tx == 1 && lk == 3)) {                 // drop x>=28 dummy columns
        const int px0 = tx*8 + lk*2;
        #pragma unroll
        for (int nn = 0; nn < 2; ++nn) {
          float q0 = fmaxf(fmaxf(fmaxf(acc[0][nn][0], acc[0][nn][1]),
                                 fmaxf(acc[1][nn][0], acc[1][nn][1])), 0.f);
          float q1 = fmaxf(fmaxf(fmaxf(acc[0][nn][2], acc[0][nn][3]),
                                 fmaxf(acc[1][nn][2], acc[1][nn][3])), 0.f);
          const int c = ntp*32 + nn*16 + l15;
          const int k0 = c*196 + py*14 + px0;      // even
          *(unsigned int*)&h3m[(k0 >> 5)*512 + (k0 & 31)] = cvtpk(q0, q1);
        }
      }
    }
  }
}

// ---------------- FC1 GEMM + fused FC2 tail ----------------
// bid = kh*32 + m4: since 32 % 8 == 0, all 8 kh-siblings of an m4 land on the
// SAME XCD (bid&7 == m4&7) -> the last-block reduction is XCD-local. Per-wave
// structure = r14 (2 A-frags, 2 B-frags, 4 MFMA/ks, full unroll). h4p stored
// THREAD-LINEAR (bid*8192 + t*16): 4x dwordx4 fully coalesced. Last-arriving
// block (per-m4 atomic counter, release/acquire threadfence) reduces the 8 kh
// partials at its own t-offsets, bias+relu -> LDS, computes fc2 for its 64
// rows. Deterministic: fixed kh-order sum; counter re-zeroed by k_prep.
__global__ __launch_bounds__(512) void k_fc1(const unsigned short* __restrict__ h3,
                                             const unsigned short* __restrict__ fc1wb,
                                             const float* __restrict__ fc1b,
                                             const float* __restrict__ fc2w,
                                             const float* __restrict__ fc2b,
                                             float* __restrict__ h4p,
                                             int* __restrict__ cnt,
                                             float* __restrict__ out) {
  __shared__ float hs[64*132];     // 33792 B, stride 132 vs bank conflicts
  __shared__ int lastflag;
  const int bid = blockIdx.x;            // kh*32 + m4
  const int kh = bid >> 5, m4 = bid & 31;
  const int t = threadIdx.x, lane = t & 63, w = t >> 6;   // w: 0..7
  const int rg = w >> 2;                 // row-group: rows m4*64 + rg*32 ..
  const int nw = w & 3;                  // n-range nw*32 ..
  const int l15 = lane & 15, lk = lane >> 4;
  const int lo = l15*32 + lk*8;          // fragment-internal offset (512 shorts)

  const unsigned short* a0p = h3 + (size_t)(m4*4 + rg*2)*200704 + (size_t)(kh*49)*512 + lo;
  const unsigned short* a1p = a0p + 200704;
  const unsigned short* b0p = fc1wb + (size_t)(kh*49)*4096 + (nw*32)*32 + lo;

  f32x4 acc00 = {0.f,0.f,0.f,0.f}, acc01 = {0.f,0.f,0.f,0.f};
  f32x4 acc10 = {0.f,0.f,0.f,0.f}, acc11 = {0.f,0.f,0.f,0.f};
  #pragma unroll
  for (int ks = 0; ks < 49; ++ks) {
    bf16x8 a0 = *(const bf16x8*)(a0p + ks*512);
    bf16x8 a1 = *(const bf16x8*)(a1p + ks*512);
    bf16x8 w0 = *(const bf16x8*)(b0p + ks*4096);
    bf16x8 w1 = *(const bf16x8*)(b0p + ks*4096 + 512);
    acc00 = __builtin_amdgcn_mfma_f32_16x16x32_bf16(a0, w0, acc00, 0, 0, 0);
    acc01 = __builtin_amdgcn_mfma_f32_16x16x32_bf16(a0, w1, acc01, 0, 0, 0);
    acc10 = __builtin_amdgcn_mfma_f32_16x16x32_bf16(a1, w0, acc10, 0, 0, 0);
    acc11 = __builtin_amdgcn_mfma_f32_16x16x32_bf16(a1, w1, acc11, 0, 0, 0);
  }
  // thread-linear coalesced partial store
  {
    float* op = h4p + (size_t)bid*8192 + t*16;
    *(f32x4*)(op + 0)  = acc00;
    *(f32x4*)(op + 4)  = acc01;
    *(f32x4*)(op + 8)  = acc10;
    *(f32x4*)(op + 12) = acc11;
  }
  __threadfence();                       // release: partials visible device-wide
  if (t == 0) lastflag = atomicAdd(&cnt[m4], 1);
  __syncthreads();
  if (lastflag != 7) return;
  __threadfence();                       // acquire side

  // ---- tail (1 of 8 blocks per m4): reduce kh, bias+relu, fc2 ----
  f32x4 v[4] = {{0.f,0.f,0.f,0.f},{0.f,0.f,0.f,0.f},{0.f,0.f,0.f,0.f},{0.f,0.f,0.f,0.f}};
  for (int k2 = 0; k2 < 8; ++k2) {
    const float* ip = h4p + (size_t)(k2*32 + m4)*8192 + t*16;
    #pragma unroll
    for (int r4 = 0; r4 < 4; ++r4) {
      f32x4 u = *(const f32x4*)(ip + r4*4);
      v[r4][0] += u[0]; v[r4][1] += u[1]; v[r4][2] += u[2]; v[r4][3] += u[3];
    }
  }
  // (t, r) -> (bb_local, n):  r = (pairhi*2+pairlo)*4 + jj
  #pragma unroll
  for (int pairhi = 0; pairhi < 2; ++pairhi)
    #pragma unroll
    for (int pairlo = 0; pairlo < 2; ++pairlo)
      #pragma unroll
      for (int jj = 0; jj < 4; ++jj) {
        const int r = (pairhi*2 + pairlo)*4 + jj;
        const int bb = rg*32 + pairhi*16 + lk*4 + jj;
        const int n  = nw*32 + pairlo*16 + l15;
        hs[bb*132 + n] = fmaxf(v[r >> 2][r & 3] + fc1b[n], 0.f);
      }
  __syncthreads();
  for (int j = t; j < 640; j += 512) {
    const int bb = j / 10, n2 = j - (j/10)*10;
    float acc = fc2b[n2];
    const float* wr = fc2w + n2*128;
    const float* hr = hs + bb*132;
    #pragma unroll 8
    for (int k = 0; k < 128; ++k) acc = fmaf(hr[k], wr[k], acc);
    out[(m4*64 + bb)*10 + n2] = acc;
  }
}

extern "C" void kernel_launch(void* const* d_in, const int* in_sizes, int n_in,
                              void* d_out, int out_size, void* d_ws, size_t ws_size,
                              hipStream_t stream) {
  const float* x    = (const float*)d_in[0];
  const float* w1   = (const float*)d_in[1];
  const float* p1   = (const float*)d_in[2];
  const float* p2   = (const float*)d_in[3];
  const float* b1   = (const float*)d_in[4];
  const float* w2   = (const float*)d_in[5];
  const float* b2   = (const float*)d_in[6];
  const float* fc1w = (const float*)d_in[7];
  const float* fc1b = (const float*)d_in[8];
  const float* fc2w = (const float*)d_in[9];
  const float* fc2b = (const float*)d_in[10];

  // ws layout (bytes):
  //        0: k1b bf16[32][32]             (2048)
  //     4096: w2b bf16[9][64][32]          (36864)
  //    40960: fc1wbF bf16[392][128][32]    (3211264)
  //  3252224: h3F bf16[128][392][16][32]   (51380224)
  // 54632448: h4p f32[256][8192]           (8388608)
  // 63021056: cnt int[32]                  (128)      -> total 63021184
  if (ws_size < 63021184u) return;
  char* ws = (char*)d_ws;
  unsigned short* k1b  = (unsigned short*)(ws + 0);
  unsigned short* w2b  = (unsigned short*)(ws + 4096);
  unsigned short* fc1wb= (unsigned short*)(ws + 40960);
  unsigned short* h3   = (unsigned short*)(ws + 3252224);
  float* h4p           = (float*)(ws + 54632448);
  int* cnt             = (int*)(ws + 63021056);

  k_prep<<<(401408 + 18432 + 1024 + 32 + 255) / 256, 256, 0, stream>>>(
      w2, fc1w, w1, p1, p2, w2b, fc1wb, k1b, cnt);
  k_conv<<<NB, 256, 0, stream>>>(x, k1b, b1, w2b, b2, h3);
  k_fc1<<<256, 512, 0, stream>>>(h3, fc1wb, fc1b, fc2w, fc2b, h4p, cnt, (float*)d_out);
}

// Round 16
// 105.793 us; speedup vs baseline: 1.8093x; 1.8093x over previous
//
#include <hip/hip_runtime.h>
#include <hip/hip_bf16.h>

typedef __attribute__((ext_vector_type(8))) short bf16x8;
typedef __attribute__((ext_vector_type(4))) float f32x4;
typedef __attribute__((ext_vector_type(4))) unsigned int u32x4;
typedef __attribute__((ext_vector_type(2))) unsigned int u32x2;

#define NB 2048

static __device__ __forceinline__ unsigned short f2bf(float f) {
  unsigned int u = __builtin_bit_cast(unsigned int, f);
  u += 0x7fffu + ((u >> 16) & 1u);   // RNE
  return (unsigned short)(u >> 16);
}
// HW packed f32->bf16 (RNE), two values into one dword
static __device__ __forceinline__ unsigned int cvtpk(float lo, float hi) {
  unsigned int r;
  asm("v_cvt_pk_bf16_f32 %0, %1, %2" : "=v"(r) : "v"(lo), "v"(hi));
  return r;
}

// ---------------- weight prep (single pass) ----------------
// fc1wbF fragment layout: idx = q*4096 + n*32 + kw   (q=k>>5, kw=k&31)
__global__ __launch_bounds__(256) void k_prep(
    const float* __restrict__ w2, const float* __restrict__ fc1w,
    const float* __restrict__ w1, const float* __restrict__ p1,
    const float* __restrict__ p2,
    unsigned short* __restrict__ w2b, unsigned short* __restrict__ fc1wb,
    unsigned short* __restrict__ k1b) {
  const int gid = blockIdx.x * blockDim.x + threadIdx.x;
  if (gid < 401408) {
    const int j0 = gid * 4;               // 4 consecutive kw, same (q, n)
    const int kw = j0 & 31;
    const int n  = (j0 >> 5) & 127;
    const int q  = j0 >> 12;
    f32x4 v = *(const f32x4*)&fc1w[n*12544 + q*32 + kw];
    u32x2 r = { cvtpk(v[0], v[1]), cvtpk(v[2], v[3]) };
    *(u32x2*)&fc1wb[j0] = r;
  } else if (gid < 401408 + 18432) {
    int i = gid - 401408;
    int cin = i & 31;
    int cout = (i >> 5) & 63;
    int kk = i >> 11;          // 0..8
    int ky = kk / 3, kx = kk % 3;
    w2b[i] = f2bf(w2[((cout*32 + cin)*3 + ky)*3 + kx]);
  } else if (gid < 401408 + 18432 + 1024) {
    int t = gid - (401408 + 18432);  // 0..1023
    int o = t >> 5, tap = t & 31;
    unsigned short r = 0;
    if (tap < 25) {
      int a = tap / 5, bcol = tap % 5;
      float acc = 0.f;
      for (int k = 0; k < 26; ++k) {
        float q1 = p1[o*26 + k] + 2.0f;
        float q2 = p2[o*26 + k] + 2.0f;
        float f1 = floorf(q1), f2 = floorf(q2);
        int idx1 = (int)f1 + ((q1 - f1) >= 0.5f ? 1 : 0);
        int idx2 = (int)f2 + ((q2 - f2) >= 0.5f ? 1 : 0);
        if (idx1 == a && idx2 == bcol) acc += w1[o*26 + k];
      }
      r = f2bf(acc);
    }
    k1b[t] = r;
  }
}

// ---------------- fused conv1(MFMA)+relu -> conv2(MFMA)+relu+maxpool ----------------
// r10 config (best measured: 68us). one block = one image; 3 blocks/CU.
// WARNING (rounds 5, 11, 15): any occupancy-raising signal (waves/EU request,
// or large-LDS-driven heuristic) collapses the compiler VGPR budget (->64 or
// 32) and spills operand fragments / kills load depth. Keep (256,3).
// k_conv is issue-bound (~44% MFMA + ~40% VALU, near-serialized); occupancy
// 25->35% (r12), LDS-read halving (r8) both neutral. Structural at ~68us.
// h1s layout: pixel-major, 4x 16B cin-blocks per pixel, XOR-swizzled.
// h3F OUTPUT fragment layout: idx = mtile*200704 + ks*512 + mi*32 + kw
__global__ __launch_bounds__(256, 3) void k_conv(
    const float* __restrict__ x, const unsigned short* __restrict__ k1b,
    const float* __restrict__ b1, const unsigned short* __restrict__ w2b,
    const float* __restrict__ b2, unsigned short* __restrict__ h3) {
  __shared__ __align__(16) float xs[32*36];              // padded input, stride 36
  __shared__ __align__(16) unsigned short h1s[16*32*32]; // one y-half, swizzled

  const int t = threadIdx.x;
  const int bimg = (blockIdx.x & 7) * 256 + (blockIdx.x >> 3);  // XCD-contiguous
  const int lane = t & 63;
  const int wid = t >> 6;
  const int l15 = lane & 15;
  const int lk = lane >> 4;

  // ---- stage x into xs (zero border) ----
  for (int i = t; i < 1152; i += 256) {
    int iy = i / 36, ix = i - iy*36;
    float v = 0.f;
    if (iy >= 2 && iy < 30 && ix >= 2 && ix < 30)
      v = x[bimg*784 + (iy-2)*28 + (ix-2)];
    xs[i] = v;
  }

  // ---- conv1 operands (registers) ----
  int off[8];                       // per-lane im2col tap offsets (taps>=25 clamp: A rows are 0 there)
  #pragma unroll
  for (int j = 0; j < 8; ++j) {
    int tp = lk*8 + j; tp = tp > 24 ? 24 : tp;
    int ky = tp / 5;
    off[j] = ky*36 + (tp - ky*5);
  }
  const bf16x8 k1a0 = *(const bf16x8*)&k1b[l15*32 + lk*8];
  const bf16x8 k1a1 = *(const bf16x8*)&k1b[(16 + l15)*32 + lk*8];
  f32x4 b1i0, b1i1;                 // MFMA acc-init with bias (row = cout = lk*4+reg)
  #pragma unroll
  for (int r = 0; r < 4; ++r) {
    b1i0[r] = b1[lk*4 + r];
    b1i1[r] = b1[16 + lk*4 + r];
  }

  // ---- conv2 operands (registers) ----
  const int ntp = wid & 1;      // couts ntp*32 .. ntp*32+31
  const int tx  = wid >> 1;     // x half-tile (wave-uniform)
  bf16x8 bfr[2][9];
  #pragma unroll
  for (int nn = 0; nn < 2; ++nn)
    #pragma unroll
    for (int kk = 0; kk < 9; ++kk)
      bfr[nn][kk] = *(const bf16x8*)&w2b[(kk*64 + (ntp*2+nn)*16 + l15)*32 + lk*8];
  f32x4 b2i[2];                 // acc-init (col = cout = l15, same across rows)
  #pragma unroll
  for (int nn = 0; nn < 2; ++nn) {
    float bb = b2[ntp*32 + nn*16 + l15];
    b2i[nn] = (f32x4){bb, bb, bb, bb};
  }
  int colOff[3];                // byte offsets into an h1s row (swizzle is row-independent)
  #pragma unroll
  for (int kx = 0; kx < 3; ++kx) {
    int xk = tx*16 + l15 + kx; xk = xk > 31 ? 31 : xk;   // clamped dummies read zero pads
    colOff[kx] = xk*64 + ((lk ^ ((xk >> 1) & 3)) << 4);
  }

  const int mtile = bimg >> 4, mi = bimg & 15;
  unsigned short* h3m = h3 + (size_t)mtile*200704 + mi*32;

  __syncthreads();

  for (int half = 0; half < 2; ++half) {
    if (half) __syncthreads();          // prev half's conv2 reads done

    // ---- zero pads for this half ----
    {
      u32x4* H = (u32x4*)h1s;
      u32x4 z = {0u,0u,0u,0u};
      const int zrow = half ? 15 : 0;   // full zero row (y'=0 / y'=29)
      if (t < 128) H[zrow*128 + t] = z;
      const int r0 = half ? 0 : 1;      // col pads on the 15 computed rows
      if (t < 240) {                    // 15 rows x 4 px x 4 chunks
        int rr = t >> 4, rem = t & 15;
        int pi = rem >> 2, sub = rem & 3;
        int px = pi == 0 ? 0 : 28 + pi; // x' in {0,29,30,31}
        H[((r0 + rr)*32 + px)*4 + sub] = z;
      }
    }

    // ---- conv1 via MFMA: A=k1[cout][tap], B=im2col[tap][pixel] ----
    const int ybase = half ? 13 : 0;
    for (int tid = wid; tid < 30; tid += 4) {
      const int ty = tid >> 1;                 // 0..14
      const int x0 = (tid & 1) << 4;
      const int yo = ybase + ty;               // conv output row
      const float* bp = &xs[yo*36 + x0 + l15];
      u32x4 bw;
      bw[0] = cvtpk(bp[off[0]], bp[off[1]]);
      bw[1] = cvtpk(bp[off[2]], bp[off[3]]);
      bw[2] = cvtpk(bp[off[4]], bp[off[5]]);
      bw[3] = cvtpk(bp[off[6]], bp[off[7]]);
      const bf16x8 bfrag = __builtin_bit_cast(bf16x8, bw);
      f32x4 d0 = b1i0, d1 = b1i1;
      d0 = __builtin_amdgcn_mfma_f32_16x16x32_bf16(k1a0, bfrag, d0, 0, 0, 0);
      d1 = __builtin_amdgcn_mfma_f32_16x16x32_bf16(k1a1, bfrag, d1, 0, 0, 0);
      // D: col=l15=pixel, row=lk*4+reg=cout -> 4 consecutive couts per lane
      const int xo = x0 + l15;
      if (xo < 28) {
        const int ry = half ? (yo - 13) : (yo + 1);
        const int pix = ry*32 + xo + 1;
        const int swz = (pix >> 1) & 3;
        const int blkbase = (lk >> 1);
        unsigned int w0lo = cvtpk(fmaxf(d0[0], 0.f), fmaxf(d0[1], 0.f));
        unsigned int w0hi = cvtpk(fmaxf(d0[2], 0.f), fmaxf(d0[3], 0.f));
        unsigned int w1lo = cvtpk(fmaxf(d1[0], 0.f), fmaxf(d1[1], 0.f));
        unsigned int w1hi = cvtpk(fmaxf(d1[2], 0.f), fmaxf(d1[3], 0.f));
        char* base = (char*)h1s + pix*64 + (lk & 1)*8;
        *(u32x2*)(base + ((blkbase ^ swz) << 4))       = (u32x2){w0lo, w0hi};
        *(u32x2*)(base + (((2 + blkbase) ^ swz) << 4)) = (u32x2){w1lo, w1hi};
      }
    }
    __syncthreads();

    // ---- conv2 via MFMA ----
    const char* h1c = (const char*)h1s;
    for (int pyl = 0; pyl < 7; ++pyl) {
      const int py = half*7 + pyl;
      const int rbase = pyl*2*2048;
      f32x4 acc[2][2];
      #pragma unroll
      for (int yi = 0; yi < 2; ++yi)
        #pragma unroll
        for (int nn = 0; nn < 2; ++nn) acc[yi][nn] = b2i[nn];
      #pragma unroll
      for (int kx = 0; kx < 3; ++kx) {
        bf16x8 af[4];
        #pragma unroll
        for (int r = 0; r < 4; ++r)
          af[r] = *(const bf16x8*)(h1c + rbase + r*2048 + colOff[kx]);
        #pragma unroll
        for (int ky = 0; ky < 3; ++ky)
          #pragma unroll
          for (int yi = 0; yi < 2; ++yi) {
            acc[yi][0] = __builtin_amdgcn_mfma_f32_16x16x32_bf16(af[yi+ky], bfr[0][ky*3+kx], acc[yi][0], 0, 0, 0);
            acc[yi][1] = __builtin_amdgcn_mfma_f32_16x16x32_bf16(af[yi+ky], bfr[1][ky*3+kx], acc[yi][1], 0, 0, 0);
          }
      }
      // pool-then-relu (monotonic), only on storing lanes
      if (!(tx == 1 && lk == 3)) {                 // drop x>=28 dummy columns
        const int px0 = tx*8 + lk*2;
        #pragma unroll
        for (int nn = 0; nn < 2; ++nn) {
          float q0 = fmaxf(fmaxf(fmaxf(acc[0][nn][0], acc[0][nn][1]),
                                 fmaxf(acc[1][nn][0], acc[1][nn][1])), 0.f);
          float q1 = fmaxf(fmaxf(fmaxf(acc[0][nn][2], acc[0][nn][3]),
                                 fmaxf(acc[1][nn][2], acc[1][nn][3])), 0.f);
          const int c = ntp*32 + nn*16 + l15;
          const int k0 = c*196 + py*14 + px0;      // even
          *(unsigned int*)&h3m[(k0 >> 5)*512 + (k0 & 31)] = cvtpk(q0, q1);
        }
      }
    }
  }
}

// ---------------- FC1 GEMM, fragment-layout operands, no LDS ----------------
// 32-row blocks (2 A-frags): 4 MFMA per ks per wave. FULL unroll at
// launch_bounds(256,2): ~200 free VGPRs of pending-load destinations so the
// scheduler keeps ~40+ dwordx4 loads in flight (covers ~900cyc HBM latency).
// fc1 sits at the A-HBM / B-L2 knee: 2x B-traffic costs +8.5us (r13),
// halving B-traffic again is neutral (r14). Do not restructure.
__global__ __launch_bounds__(256, 2) void k_fc1(const unsigned short* __restrict__ h3,
                                                const unsigned short* __restrict__ fc1wb,
                                                float* __restrict__ h4p) {
  const int bid = blockIdx.x;            // 64 m2-tiles x 8 kh (kh = XCD -> B L2-hot)
  const int m2 = bid >> 3, kh = bid & 7;
  const int t = threadIdx.x, lane = t & 63, w = t >> 6;
  const int l15 = lane & 15, lk = lane >> 4;
  const int lo = l15*32 + lk*8;          // fragment-internal offset (512 shorts)

  const unsigned short* a0p = h3 + (size_t)(2*m2)*200704 + (size_t)(kh*49)*512 + lo;
  const unsigned short* a1p = a0p + 200704;
  const unsigned short* b0p = fc1wb + (size_t)(kh*49)*4096 + (w*32)*32 + lo;

  f32x4 acc00 = {0.f,0.f,0.f,0.f}, acc01 = {0.f,0.f,0.f,0.f};
  f32x4 acc10 = {0.f,0.f,0.f,0.f}, acc11 = {0.f,0.f,0.f,0.f};
  #pragma unroll
  for (int ks = 0; ks < 49; ++ks) {
    bf16x8 a0 = *(const bf16x8*)(a0p + ks*512);
    bf16x8 a1 = *(const bf16x8*)(a1p + ks*512);
    bf16x8 w0 = *(const bf16x8*)(b0p + ks*4096);
    bf16x8 w1 = *(const bf16x8*)(b0p + ks*4096 + 512);
    acc00 = __builtin_amdgcn_mfma_f32_16x16x32_bf16(a0, w0, acc00, 0, 0, 0);
    acc01 = __builtin_amdgcn_mfma_f32_16x16x32_bf16(a0, w1, acc01, 0, 0, 0);
    acc10 = __builtin_amdgcn_mfma_f32_16x16x32_bf16(a1, w0, acc10, 0, 0, 0);
    acc11 = __builtin_amdgcn_mfma_f32_16x16x32_bf16(a1, w1, acc11, 0, 0, 0);
  }
  float* outp = h4p + (size_t)kh * NB * 128;
  const int n0 = w*32 + l15;
  const int bb0 = m2*32 + lk*4;
  #pragma unroll
  for (int jj = 0; jj < 4; ++jj) {
    outp[(bb0 + jj)*128 + n0]           = acc00[jj];
    outp[(bb0 + jj)*128 + n0 + 16]      = acc01[jj];
    outp[(bb0 + 16 + jj)*128 + n0]      = acc10[jj];
    outp[(bb0 + 16 + jj)*128 + n0 + 16] = acc11[jj];
  }
}

// ---------------- K-partial reduce + bias + relu + FC2 ----------------
__global__ __launch_bounds__(256) void k_fc2(const float* __restrict__ h4p,
                                             const float* __restrict__ fc1b,
                                             const float* __restrict__ fc2w,
                                             const float* __restrict__ fc2b,
                                             float* __restrict__ out) {
  __shared__ float hs[8*129];
  const int blk = blockIdx.x;    // 256 blocks x 8 batches
  const int t = threadIdx.x;
  for (int i = t; i < 1024; i += 256) {
    const int base = blk*1024 + i;
    float v = 0.f;
    #pragma unroll
    for (int kh = 0; kh < 8; ++kh) v += h4p[base + kh*262144];
    v += fc1b[i & 127];
    hs[(i >> 7)*129 + (i & 127)] = fmaxf(v, 0.f);
  }
  __syncthreads();
  if (t < 80) {
    const int bb = t / 10, n = t - (t/10)*10;
    float acc = fc2b[n];
    const float* wr = fc2w + n*128;
    const float* hr = hs + bb*129;
    #pragma unroll 8
    for (int k = 0; k < 128; ++k) acc = fmaf(hr[k], wr[k], acc);
    out[(blk*8 + bb)*10 + n] = acc;
  }
}

extern "C" void kernel_launch(void* const* d_in, const int* in_sizes, int n_in,
                              void* d_out, int out_size, void* d_ws, size_t ws_size,
                              hipStream_t stream) {
  const float* x    = (const float*)d_in[0];
  const float* w1   = (const float*)d_in[1];
  const float* p1   = (const float*)d_in[2];
  const float* p2   = (const float*)d_in[3];
  const float* b1   = (const float*)d_in[4];
  const float* w2   = (const float*)d_in[5];
  const float* b2   = (const float*)d_in[6];
  const float* fc1w = (const float*)d_in[7];
  const float* fc1b = (const float*)d_in[8];
  const float* fc2w = (const float*)d_in[9];
  const float* fc2b = (const float*)d_in[10];

  // ws layout (bytes):
  //        0: k1b bf16[32][32]             (2048)
  //     4096: w2b bf16[9][64][32]          (36864)
  //    40960: fc1wbF bf16[392][128][32]    (3211264)
  //  3252224: h3F bf16[128][392][16][32]   (51380224)
  // 54632448: h4p f32[8][2048][128]        (8388608)  -> total 63021056
  if (ws_size < 63021056u) return;
  char* ws = (char*)d_ws;
  unsigned short* k1b  = (unsigned short*)(ws + 0);
  unsigned short* w2b  = (unsigned short*)(ws + 4096);
  unsigned short* fc1wb= (unsigned short*)(ws + 40960);
  unsigned short* h3   = (unsigned short*)(ws + 3252224);
  float* h4p           = (float*)(ws + 54632448);

  k_prep<<<(401408 + 18432 + 1024 + 255) / 256, 256, 0, stream>>>(
      w2, fc1w, w1, p1, p2, w2b, fc1wb, k1b);
  k_conv<<<NB, 256, 0, stream>>>(x, k1b, b1, w2b, b2, h3);
  k_fc1<<<512, 256, 0, stream>>>(h3, fc1wb, h4p);
  k_fc2<<<256, 256, 0, stream>>>(h4p, fc1b, fc2w, fc2b, (float*)d_out);
}